// Round 1
// baseline (97.937 us; speedup 1.0000x reference)
//
#include <hip/hip_runtime.h>

// CombinedLoss: 0.99 * dice + 0.01 * mean(phi * sigmoid(pred))
// phi = signed exact EDT of targets mask (16 x 512 x 512), |phi|>1e5 -> 0.
//
// Round 4: capped bit-mask EDT. Key insight: the column lower-envelope only
// ever consumes row distances g <= 17 (g >= 18 implies d^2 >= 324 > 289, which
// routes to the exact global fallback regardless). So phase 1 builds a 512-bit
// site mask per row (64 B) and derives each pixel's capped opposite-class row
// distance from a +-17-bit window with clz/ctz — no 64-lane shuffle prefix
// scans. Result stored as ONE byte/pixel (2-bit class, 6-bit distance; the
// own-class distance is always 0). LDS drops 128 KB -> ~28 KB, so the grid is
// 512 blocks x 512 threads (BH=16 slabs, 2 blocks/CU, 4 waves/SIMD) instead of
// 1 block/CU at 2 waves/SIMD. Phase 2 runs the envelope in 24-bit integer ops
// from u32 byte-quad LDS reads. Any pixel unresolved past the halo (never on
// Bernoulli(0.5) data) takes the exact global fallback, so the kernel is exact
// for ANY input.
//
// ws: double partials[512][4] at offset 0 (fully rewritten every call).

#define HH 512
#define WW 512
#define BH 16      // output rows per block
#define HALO 16
#define TR 48      // LDS tile rows = BH + 2*HALO
#define NT 512     // threads per block
#define NBLK 512   // 16 images * 32 slabs
#define NGRP 4     // BH*WW / (NT*4)

// exact per-pixel fallback: full-image search with pruning (ultra-rare path)
__device__ float fallback_exact(const int* __restrict__ t, int n, int y, int x,
                                bool fg, float m2) {
    const int* tn = t + (n << 18);
    for (int yy = 0; yy < HH; ++yy) {
        float dy = (float)(yy - y);
        float dy2 = dy * dy;
        if (dy2 >= m2) continue;
        const int* row = tn + (yy << 9);
        int lim = (int)sqrtf(m2 - dy2);
        if (lim > WW) lim = WW;
        for (int dx = 0; dx <= lim; ++dx) {
            bool hit = false;
            int xl = x - dx, xr = x + dx;
            if (xl >= 0) { int v = row[xl]; hit = fg ? (v == 0) : (v != 0); }
            if (!hit && xr < WW) { int v = row[xr]; hit = fg ? (v == 0) : (v != 0); }
            if (hit) {
                float c = fmaf((float)dx, (float)dx, dy2);
                if (c < m2) m2 = c;
                break;
            }
        }
    }
    return m2;
}

__global__ __launch_bounds__(NT, 4) void edt_fused(const int* __restrict__ t,
                                                   const float* __restrict__ pred,
                                                   double* __restrict__ partials) {
    __shared__ unsigned long long msk[TR][8];   // 3 KB: fg-site bit per pixel
    __shared__ unsigned char gb[TR][WW];        // 24 KB: class(2b) | capped g(6b)
    __shared__ double sred[8][4];

    const int n     = blockIdx.x >> 5;
    const int y0    = (blockIdx.x & 31) << 4;
    const int rbase = y0 - HALO;
    const int wave  = threadIdx.x >> 6;   // 0..7
    const int lane  = threadIdx.x & 63;
    const int x0    = lane << 3;

    // ---------------- phase 1a: build per-row 512-bit site masks ----------------
    for (int rr = wave; rr < TR; rr += 8) {
        const int gy = rbase + rr;
        if (gy < 0 || gy >= HH) continue;   // OOR rows handled in 1b
        const int4* tp = (const int4*)(t + (n << 18) + (gy << 9) + x0);
        int4 ta = tp[0], tb = tp[1];
        unsigned int byte = 0;
        byte |= (unsigned int)(ta.x != 0) << 0;
        byte |= (unsigned int)(ta.y != 0) << 1;
        byte |= (unsigned int)(ta.z != 0) << 2;
        byte |= (unsigned int)(ta.w != 0) << 3;
        byte |= (unsigned int)(tb.x != 0) << 4;
        byte |= (unsigned int)(tb.y != 0) << 5;
        byte |= (unsigned int)(tb.z != 0) << 6;
        byte |= (unsigned int)(tb.w != 0) << 7;
        ((unsigned char*)&msk[rr][0])[lane] = (unsigned char)byte;
    }
    __syncthreads();

    // ---------------- phase 1b: capped 1D row distances -> bytes ----------------
    // lane covers pixels [x0, x0+7]; window = mask bits [x0-24, x0+39] (covers
    // +-17 around every covered pixel). Bits outside [0,512) masked invalid for
    // BOTH classes via V.
    {
        const int s  = (lane - 3) << 3;      // window start bit (may be <0)
        const int sh = s & 63;
        const int j0 = s >> 6;               // arithmetic shift: -24>>6 = -1
        unsigned long long V = ~0ull;
        if (s < 0)   V &= (~0ull) << (-s);
        if (s > 448) V &= (~0ull) >> (s - 448);   // s+64 > 512

        for (int rr = wave; rr < TR; rr += 8) {
            const int gy = rbase + rr;
            unsigned long long pk;
            if (gy < 0 || gy >= HH) {
                pk = 0xBFBFBFBFBFBFBFBFull;   // class=2 (OOR), g=63: far for both fields
            } else {
                unsigned long long w0 = (j0 >= 0) ? msk[rr][j0] : 0ull;
                unsigned long long w1 = (j0 < 7) ? msk[rr][j0 + 1] : 0ull;
                unsigned long long win = sh ? ((w0 >> sh) | (w1 << (64 - sh))) : w0;
                pk = 0ull;
#pragma unroll
                for (int i = 0; i < 8; ++i) {
                    const int c = 24 + i;                       // center bit of pixel i
                    unsigned int b = (unsigned int)(win >> c) & 1u;  // own class
                    unsigned long long mm = (b ? ~win : win) & V;    // opposite-class sites
                    unsigned long long lo = mm & ((1ull << c) - 1ull);
                    unsigned long long hi = mm >> (c + 1);
                    int dl = lo ? (c - 63 + __builtin_clzll(lo)) : 64;
                    int dr = hi ? (1 + (int)__builtin_ctzll(hi)) : 64;
                    int g = min(min(dl, dr), 63);               // >17 == "far" sentinel
                    pk |= ((unsigned long long)((b << 6) | (unsigned int)g)) << (i * 8);
                }
            }
            *((unsigned long long*)&gb[rr][x0]) = pk;
        }
    }
    __syncthreads();

    // ---------------- phase 2: integer column envelope + fused loss ----------------
    double s_b = 0.0, s_p = 0.0, s_i = 0.0;
    int s_t = 0;

#pragma unroll 1
    for (int grp = 0; grp < NGRP; ++grp) {
        const int pid = (grp * NT + threadIdx.x) << 2;   // 4 consecutive px
        const int yl  = pid >> 9;                        // 0..15
        const int x   = pid & 511;
        const int r   = yl + HALO;                       // 16..31 -> r+-16 in [0,47]

        const float4 p4 = *((const float4*)(pred + (n << 18) + ((y0 + yl) << 9) + x));
        const float pv[4] = {p4.x, p4.y, p4.z, p4.w};

        const unsigned int ow = *((const unsigned int*)&gb[r][x]);
        int  m2[4], wc[4];
        bool fg[4];
        int  mx = 0;
#pragma unroll
        for (int j = 0; j < 4; ++j) {
            unsigned int bj  = (ow >> (8 * j)) & 255u;
            unsigned int cls = bj >> 6;
            int gg = (int)(bj & 63u);
            fg[j] = (cls == 1u);
            wc[j] = fg[j] ? 0 : 1;     // class code whose presence means distance 0
            m2[j] = gg * gg;
            mx = max(mx, m2[j]);
        }

        for (int k = 1; k <= HALO; ++k) {
            const int k2 = k * k;
            if (k2 >= mx) break;
            const unsigned int bd = *((const unsigned int*)&gb[r - k][x]);
            const unsigned int bu = *((const unsigned int*)&gb[r + k][x]);
            mx = 0;
#pragma unroll
            for (int j = 0; j < 4; ++j) {
                if (k2 < m2[j]) {
                    unsigned int dj = (bd >> (8 * j)) & 255u;
                    unsigned int uj = (bu >> (8 * j)) & 255u;
                    int a = ((int)(dj >> 6) == wc[j]) ? 0 : (int)(dj & 63u);
                    int b = ((int)(uj >> 6) == wc[j]) ? 0 : (int)(uj & 63u);
                    m2[j] = min(m2[j], min(a * a + k2, b * b + k2));
                }
                mx = max(mx, m2[j]);
            }
        }

        float df[4];
#pragma unroll
        for (int j = 0; j < 4; ++j) df[j] = sqrtf((float)m2[j]);

        if (mx > 289) {   // some pixel unresolved past cap/halo (never on random data)
#pragma unroll
            for (int j = 0; j < 4; ++j)
                if (m2[j] > 289) {
                    // pass huge bound: capped m2 is sentinel-inflated, not a true bound
                    float fm2 = fallback_exact(t, n, y0 + yl, x + j, fg[j], 1.0e12f);
                    df[j] = sqrtf(fm2);
                }
        }

#pragma unroll
        for (int j = 0; j < 4; ++j) {
            float p = 1.0f / (1.0f + expf(-pv[j]));
            float phi = fg[j] ? -df[j] : df[j];
            if (df[j] > 1.0e4f) phi = 0.0f;   // "no sites" case only; matches |phi|>1e5 -> 0
            s_b += (double)(phi * p);
            s_p += (double)p;
            if (fg[j]) { s_i += (double)p; s_t += 1; }
        }
    }
    double s_tt = (double)s_t;

    // ---------------- block reduce ----------------
#pragma unroll
    for (int off = 32; off > 0; off >>= 1) {
        s_b  += __shfl_xor(s_b,  off, 64);
        s_p  += __shfl_xor(s_p,  off, 64);
        s_i  += __shfl_xor(s_i,  off, 64);
        s_tt += __shfl_xor(s_tt, off, 64);
    }
    if (lane == 0) {
        sred[wave][0] = s_b; sred[wave][1] = s_p; sred[wave][2] = s_i; sred[wave][3] = s_tt;
    }
    __syncthreads();
    if (threadIdx.x == 0) {
        double* dst = partials + (size_t)blockIdx.x * 4;
#pragma unroll
        for (int c = 0; c < 4; ++c) {
            double acc = 0.0;
#pragma unroll
            for (int wv = 0; wv < 8; ++wv) acc += sred[wv][c];
            dst[c] = acc;
        }
    }
}

// ---------------- finalize: 512 partial rows -> loss scalar ----------------
__global__ __launch_bounds__(512) void finalize_loss(const double* __restrict__ partials,
                                                     float* __restrict__ out) {
    const int wave = threadIdx.x >> 6;
    const int lane = threadIdx.x & 63;
    const double* src = partials + (size_t)threadIdx.x * 4;
    double s0 = src[0], s1 = src[1], s2 = src[2], s3 = src[3];
#pragma unroll
    for (int off = 32; off > 0; off >>= 1) {
        s0 += __shfl_xor(s0, off, 64);
        s1 += __shfl_xor(s1, off, 64);
        s2 += __shfl_xor(s2, off, 64);
        s3 += __shfl_xor(s3, off, 64);
    }
    __shared__ double red[8][4];
    if (lane == 0) { red[wave][0] = s0; red[wave][1] = s1; red[wave][2] = s2; red[wave][3] = s3; }
    __syncthreads();
    if (threadIdx.x == 0) {
        double sb = 0.0, sp = 0.0, si = 0.0, st = 0.0;
#pragma unroll
        for (int wv = 0; wv < 8; ++wv) {
            sb += red[wv][0]; sp += red[wv][1]; si += red[wv][2]; st += red[wv][3];
        }
        double dice = 1.0 - (2.0 * si + 1e-6) / (sp + st + 1e-6);
        double boundary = sb / (double)(16 * 512 * 512);
        out[0] = (float)(0.99 * dice + 0.01 * boundary);
    }
}

extern "C" void kernel_launch(void* const* d_in, const int* in_sizes, int n_in,
                              void* d_out, int out_size, void* d_ws, size_t ws_size,
                              hipStream_t stream) {
    const float* pred = (const float*)d_in[0];
    const int*   targ = (const int*)d_in[1];
    double* partials = (double*)d_ws;        // 512 * 4 doubles, fully rewritten
    float* out = (float*)d_out;

    edt_fused<<<NBLK, NT, 0, stream>>>(targ, pred, partials);
    finalize_loss<<<1, 512, 0, stream>>>(partials, out);
}